// Round 21
// baseline (5462.279 us; speedup 1.0000x reference)
//
#include <hip/hip_runtime.h>
#include <hip/hip_cooperative_groups.h>

namespace cg = cooperative_groups;

typedef unsigned short u16;
constexpr int Ss = 128, Hn = 1024, En = 512, Cn = 512, Vn = 32000;
constexpr size_t PL = 1024u * 1024u;

using short8 = __attribute__((ext_vector_type(8))) short;
using f32x4  = __attribute__((ext_vector_type(4))) float;

// ---- static device scratch (all planes rewritten in-launch before read) ----
__device__ __align__(1024) u16 g_hh[2][PL];   // h ping-pong, hi
__device__ __align__(1024) u16 g_hl[2][PL];   // h ping-pong, lo
__device__ __align__(1024) u16 g_yh[PL], g_yl[PL];
__device__ __align__(1024) u16 g_zh[PL], g_zl[PL];
__device__ __align__(1024) float g_proj[(size_t)Vn * Hn];  // emb@Wih^T + bih + bhh
// bf16 hi/lo split tables (recomputed every launch; deterministic)
__device__ __align__(1024) u16 t_eh[(size_t)Vn * En], t_el[(size_t)Vn * En];
__device__ __align__(1024) u16 t_xh[(size_t)Hn * En], t_xl[(size_t)Hn * En];  // Wih
__device__ __align__(1024) u16 t_hh[(size_t)Hn * Hn], t_hl[(size_t)Hn * Hn];  // Whh
__device__ __align__(1024) u16 t_1h[(size_t)Hn * Hn], t_1l[(size_t)Hn * Hn];  // W1
__device__ __align__(1024) u16 t_2h[(size_t)Cn * Hn], t_2l[(size_t)Cn * Hn];  // W2

__device__ __forceinline__ void gl16(const void* g, void* l) {
  __builtin_amdgcn_global_load_lds((const __attribute__((address_space(1))) void*)g,
                                   (__attribute__((address_space(3))) void*)l, 16, 0, 0);
}
__device__ __forceinline__ unsigned f2bf(float f) {
  unsigned u = __float_as_uint(f);
  return (u + 0x7fffu + ((u >> 16) & 1u)) >> 16;
}
__device__ __forceinline__ float bf2f(unsigned u) { return __uint_as_float(u << 16); }

__global__ void cvt_split(const float* __restrict__ src, int which, int n) {
  u16 *hi, *lo;
  switch (which) {
    case 0: hi = t_eh; lo = t_el; break;
    case 1: hi = t_xh; lo = t_xl; break;
    case 2: hi = t_hh; lo = t_hl; break;
    case 3: hi = t_1h; lo = t_1l; break;
    default: hi = t_2h; lo = t_2l; break;
  }
  for (int i = blockIdx.x * blockDim.x + threadIdx.x; i < n; i += gridDim.x * blockDim.x) {
    const float v = src[i];
    const unsigned h = f2bf(v);
    hi[i] = (u16)h;
    lo[i] = (u16)f2bf(v - bf2f(h));
  }
}

// Shared GEMM-tile prolog (16x16 shape; proj_k / mlp_k — unchanged, green).
#define GEMM_PROLOG_NOBID()                                                    \
  const int tid = threadIdx.x;                                                 \
  const int w = tid >> 6, l = tid & 63;                                        \
  const int wr = w & 3, wc = w >> 2;                                           \
  const int lrow = l & 15, lk = l >> 4;                                        \
  const int sr = tid >> 3, p = tid & 7;                                        \
  const int sby = ((p ^ (sr & 7)) << 4);                                       \
  const int arow = (wr << 4) + lrow;                                           \
  int aoff[2], bboff[2][2];                                                    \
  _Pragma("unroll") for (int s = 0; s < 2; ++s)                                \
      aoff[s] = arow * 128 + ((s * 64 + lk * 16) ^ ((arow & 7) << 4));         \
  _Pragma("unroll") for (int n = 0; n < 2; ++n) {                              \
    const int jl = (wc << 5) + (n << 4) + lrow;                                \
    _Pragma("unroll") for (int s = 0; s < 2; ++s)                              \
        bboff[n][s] = jl * 128 + ((s * 64 + lk * 16) ^ ((jl & 7) << 4));       \
  }
#define GEMM_PROLOG() const int bid = blockIdx.x; GEMM_PROLOG_NOBID()

#define GEMM_MFMA(ca, cb)                                                      \
  _Pragma("unroll") for (int s = 0; s < 2; ++s) {                              \
    short8 a = *(const short8*)((ca) + aoff[s]);                               \
    _Pragma("unroll") for (int n = 0; n < 2; ++n) {                            \
      short8 b = *(const short8*)((cb) + bboff[n][s]);                         \
      acc[n] = __builtin_amdgcn_mfma_f32_16x16x32_bf16(a, b, acc[n], 0, 0, 0); \
    }                                                                          \
  }

// proj[v][j] = emb[v] @ Wih^T + bih[j] + bhh[j]   (unchanged from r15, green)
__global__ void __launch_bounds__(512) proj_k(const float* __restrict__ bih,
                                              const float* __restrict__ bhh) {
  __shared__ char ring[65536];   // 2 slots x {Eh 8K | El 8K | Xh 8K | Xl 8K}
  GEMM_PROLOG()
  const int v0 = (bid % 500) << 6;
  const int j0 = (bid / 500) << 6;

  f32x4 acc[2];
#pragma unroll
  for (int n = 0; n < 2; ++n) {
    const float bs = bih[j0 + (wc << 5) + (n << 4) + lrow] +
                     bhh[j0 + (wc << 5) + (n << 4) + lrow];
#pragma unroll
    for (int ri = 0; ri < 4; ++ri) acc[n][ri] = bs;
  }

  auto stage = [&](int c) {
    char* sl = ring + (c & 1) * 32768;
    const int kb = c * 128;
    gl16((const char*)t_eh + (size_t)(v0 + sr) * 1024 + kb + sby, sl + w * 1024);
    gl16((const char*)t_el + (size_t)(v0 + sr) * 1024 + kb + sby, sl + 8192 + w * 1024);
    gl16((const char*)t_xh + (size_t)(j0 + sr) * 1024 + kb + sby, sl + 16384 + w * 1024);
    gl16((const char*)t_xl + (size_t)(j0 + sr) * 1024 + kb + sby, sl + 24576 + w * 1024);
  };
  stage(0); stage(1);
  for (int c = 0; c < 8; ++c) {
    if (c < 7) asm volatile("s_waitcnt vmcnt(4)" ::: "memory");
    else       asm volatile("s_waitcnt vmcnt(0)" ::: "memory");
    __builtin_amdgcn_s_barrier();
    __builtin_amdgcn_sched_barrier(0);
    const char* sl = ring + (c & 1) * 32768;
#pragma unroll
    for (int s = 0; s < 2; ++s) {
      short8 aH = *(const short8*)(sl + aoff[s]);
      short8 aL = *(const short8*)(sl + 8192 + aoff[s]);
#pragma unroll
      for (int n = 0; n < 2; ++n) {
        short8 bH = *(const short8*)(sl + 16384 + bboff[n][s]);
        short8 bL = *(const short8*)(sl + 24576 + bboff[n][s]);
        acc[n] = __builtin_amdgcn_mfma_f32_16x16x32_bf16(aH, bH, acc[n], 0, 0, 0);
        acc[n] = __builtin_amdgcn_mfma_f32_16x16x32_bf16(aL, bH, acc[n], 0, 0, 0);
        acc[n] = __builtin_amdgcn_mfma_f32_16x16x32_bf16(aH, bL, acc[n], 0, 0, 0);
      }
    }
    __builtin_amdgcn_s_barrier();
    if (c + 2 < 8) stage(c + 2);
  }
#pragma unroll
  for (int n = 0; n < 2; ++n) {
    const int j = j0 + (wc << 5) + (n << 4) + lrow;
#pragma unroll
    for (int ri = 0; ri < 4; ++ri)
      g_proj[(size_t)(v0 + (wr << 4) + lk * 4 + ri) * 1024 + j] = acc[n][ri];
  }
}

// Persistent RNN scan. r21 = r16's step_k inner loop VERBATIM (16 k=64 chunks,
// ring-4, dist-3, counted vmcnt, 1 barrier/chunk) looped over t with
// grid.sync() replacing the 128 kernel launches. __syncthreads after the toks
// load drains the previous tail's stores -> iter-0 ledger identical to r16.
__global__ void __launch_bounds__(512) scan_k(const int* __restrict__ x_in,
                                              const int* __restrict__ x_len) {
  cg::grid_group grid = cg::this_grid();
  extern __shared__ char ring[];   // 4 slots x {Ah 8K | Al 8K | Wh 8K | Wl 8K}
  __shared__ int toks[64];
  const int tid = threadIdx.x, bid = blockIdx.x;
  const int w = tid >> 6, l = tid & 63;
  const int wr = w & 3, wc = w >> 2;
  const int lrow = l & 15, lk = l >> 4;
  const int sr = tid >> 3, p = tid & 7;
  const int sby = ((p ^ (sr & 7)) << 4);
  const int b0 = (bid & 15) << 6, j0 = (bid >> 4) << 6;

  const int arow = (wr << 4) + lrow;
  int aoff[2], bboff[2][2];
#pragma unroll
  for (int s = 0; s < 2; ++s)
    aoff[s] = arow * 128 + ((s * 64 + lk * 16) ^ ((arow & 7) << 4));
#pragma unroll
  for (int n = 0; n < 2; ++n) {
    const int jl = (wc << 5) + (n << 4) + lrow;
#pragma unroll
    for (int s = 0; s < 2; ++s)
      bboff[n][s] = jl * 128 + ((s * 64 + lk * 16) ^ ((jl & 7) << 4));
  }
  int lenv[4];
#pragma unroll
  for (int ri = 0; ri < 4; ++ri) lenv[ri] = x_len[b0 + (wr << 4) + lk * 4 + ri];

  for (int t = 0; t < Ss; ++t) {
    const u16* hinh = g_hh[t & 1];
    const u16* hinl = g_hl[t & 1];
    u16* houth = g_hh[(t + 1) & 1];
    u16* houtl = g_hl[(t + 1) & 1];

    if (tid < 64) toks[tid] = x_in[(b0 + tid) * Ss + t];
    __syncthreads();   // drains prev tail stores + toks -> vmcnt 0 here

    // pj gathers issued FIRST (oldest vmcnt entries; drained by iter-0's wait)
    float pj[2][4];
#pragma unroll
    for (int n = 0; n < 2; ++n) {
      const int j = j0 + (wc << 5) + (n << 4) + lrow;
#pragma unroll
      for (int ri = 0; ri < 4; ++ri)
        pj[n][ri] = g_proj[(size_t)toks[(wr << 4) + lk * 4 + ri] * 1024 + j];
    }
    asm volatile("" ::: "memory");

    f32x4 acc[2];
    acc[0] = (f32x4){0.f, 0.f, 0.f, 0.f}; acc[1] = acc[0];

    if (t > 0) {
      auto stage = [&](int c) {
        char* sl = ring + (c & 3) * 32768;
        const int kb = c * 128;
        gl16((const char*)hinh + (size_t)(b0 + sr) * 2048 + kb + sby, sl + w * 1024);
        gl16((const char*)hinl + (size_t)(b0 + sr) * 2048 + kb + sby, sl + 8192 + w * 1024);
        gl16((const char*)t_hh + (size_t)(j0 + sr) * 2048 + kb + sby, sl + 16384 + w * 1024);
        gl16((const char*)t_hl + (size_t)(j0 + sr) * 2048 + kb + sby, sl + 24576 + w * 1024);
      };
      stage(0); stage(1); stage(2);
      for (int c = 0; c < 16; ++c) {
        const int left = 15 - c;
        if (left >= 2)      asm volatile("s_waitcnt vmcnt(8)" ::: "memory");
        else if (left == 1) asm volatile("s_waitcnt vmcnt(4)" ::: "memory");
        else                asm volatile("s_waitcnt vmcnt(0)" ::: "memory");
        __builtin_amdgcn_s_barrier();          // chunk c staged by ALL waves;
                                               // also: all slot-(c-1) reads done
        __builtin_amdgcn_sched_barrier(0);     // rule #18
        if (c + 3 < 16) stage(c + 3);          // overwrite slot (c-1)&3: safe
        const char* sl = ring + (c & 3) * 32768;
#pragma unroll
        for (int s = 0; s < 2; ++s) {
          short8 aH = *(const short8*)(sl + aoff[s]);
          short8 aL = *(const short8*)(sl + 8192 + aoff[s]);
#pragma unroll
          for (int n = 0; n < 2; ++n) {
            short8 bH = *(const short8*)(sl + 16384 + bboff[n][s]);
            short8 bL = *(const short8*)(sl + 24576 + bboff[n][s]);
            acc[n] = __builtin_amdgcn_mfma_f32_16x16x32_bf16(aH, bH, acc[n], 0, 0, 0);
            acc[n] = __builtin_amdgcn_mfma_f32_16x16x32_bf16(aL, bH, acc[n], 0, 0, 0);
            acc[n] = __builtin_amdgcn_mfma_f32_16x16x32_bf16(aH, bL, acc[n], 0, 0, 0);
          }
        }
      }
    }

    // tail: tanh, split-store h, y-capture
#pragma unroll
    for (int n = 0; n < 2; ++n) {
      const int j = j0 + (wc << 5) + (n << 4) + lrow;
#pragma unroll
      for (int ri = 0; ri < 4; ++ri) {
        const int brow = b0 + (wr << 4) + lk * 4 + ri;
        const float v = tanhf(acc[n][ri] + pj[n][ri]);
        const unsigned hi = f2bf(v);
        const unsigned lo = f2bf(v - bf2f(hi));
        const size_t off = (size_t)brow * 1024 + j;
        houth[off] = (u16)hi;
        houtl[off] = (u16)lo;
        if (lenv[ri] == t + 1) { g_yh[off] = (u16)hi; g_yl[off] = (u16)lo; }
      }
    }
    grid.sync();   // h visibility (device-scope) + step ordering
  }
}

// MLP (unchanged from r12, green)
__global__ void __launch_bounds__(512) mlp_k(const float* __restrict__ bias,
                                             float* __restrict__ out, int mode) {
  __shared__ char sA[16384];
  __shared__ char sB[16384];
  GEMM_PROLOG()
  const int b0 = (bid & 15) << 6, j0 = (bid >> 4) << 6;
  const u16* ah = mode ? g_zh : g_yh;
  const u16* al = mode ? g_zl : g_yl;
  const u16* bh = mode ? t_2h : t_1h;
  const u16* bl = mode ? t_2l : t_1l;

  f32x4 acc[2];
#pragma unroll
  for (int n = 0; n < 2; ++n) {
    const float bs = bias[j0 + (wc << 5) + (n << 4) + lrow];
#pragma unroll
    for (int ri = 0; ri < 4; ++ri) acc[n][ri] = bs;
  }

  auto stage = [&](int c) {
    char* da = sA + (c & 1) * 8192;
    char* db = sB + (c & 1) * 8192;
    const u16* ap = (c >= 16 && c < 32) ? al : ah;
    const u16* bp = (c < 32) ? bh : bl;
    const int kb = (c & 15) * 128;
    gl16((const char*)ap + (size_t)(b0 + sr) * 2048 + kb + sby, da + w * 1024);
    gl16((const char*)bp + (size_t)(j0 + sr) * 2048 + kb + sby, db + w * 1024);
  };
  stage(0);
  __syncthreads();
  for (int c = 0; c < 48; ++c) {
    const char* ca = sA + (c & 1) * 8192;
    const char* cb = sB + (c & 1) * 8192;
    if (c < 47) stage(c + 1);
    GEMM_MFMA(ca, cb)
    __syncthreads();
  }

#pragma unroll
  for (int n = 0; n < 2; ++n) {
    const int j = j0 + (wc << 5) + (n << 4) + lrow;
#pragma unroll
    for (int ri = 0; ri < 4; ++ri) {
      const int brow = b0 + (wr << 4) + lk * 4 + ri;
      if (mode == 0) {
        const float v = fmaxf(acc[n][ri], 0.f);
        const unsigned hi = f2bf(v);
        const unsigned lo = f2bf(v - bf2f(hi));
        const size_t off = (size_t)brow * 1024 + j;
        g_zh[off] = (u16)hi;
        g_zl[off] = (u16)lo;
      } else {
        out[(size_t)brow * 512 + j] = acc[n][ri];
      }
    }
  }
}

extern "C" void kernel_launch(void* const* d_in, const int* in_sizes, int n_in,
                              void* d_out, int out_size, void* d_ws, size_t ws_size,
                              hipStream_t stream) {
  const int*   x_in  = (const int*)d_in[0];
  const int*   x_len = (const int*)d_in[1];
  const float* emb = (const float*)d_in[2];
  const float* Wih = (const float*)d_in[3];
  const float* Whh = (const float*)d_in[4];
  const float* bih = (const float*)d_in[5];
  const float* bhh = (const float*)d_in[6];
  const float* W1  = (const float*)d_in[7];
  const float* b1  = (const float*)d_in[8];
  const float* W2  = (const float*)d_in[9];
  const float* b2  = (const float*)d_in[10];
  float* out = (float*)d_out;

  (void)hipFuncSetAttribute((const void*)scan_k,
                            hipFuncAttributeMaxDynamicSharedMemorySize, 131072);

  cvt_split<<<dim3(4096), dim3(256), 0, stream>>>(emb, 0, Vn * En);
  cvt_split<<<dim3(1024), dim3(256), 0, stream>>>(Wih, 1, Hn * En);
  cvt_split<<<dim3(2048), dim3(256), 0, stream>>>(Whh, 2, Hn * Hn);
  cvt_split<<<dim3(2048), dim3(256), 0, stream>>>(W1, 3, Hn * Hn);
  cvt_split<<<dim3(1024), dim3(256), 0, stream>>>(W2, 4, Cn * Hn);

  proj_k<<<dim3(8000), dim3(512), 0, stream>>>(bih, bhh);

  void* args[] = {(void*)&x_in, (void*)&x_len};
  (void)hipLaunchCooperativeKernel((const void*)scan_k, dim3(256), dim3(512),
                                   args, 131072, stream);

  mlp_k<<<dim3(256), dim3(512), 0, stream>>>(b1, nullptr, 0);
  mlp_k<<<dim3(128), dim3(512), 0, stream>>>(b2, out, 1);
}

// Round 22
// 1691.531 us; speedup vs baseline: 3.2292x; 3.2292x over previous
//
#include <hip/hip_runtime.h>

typedef unsigned short u16;
constexpr int Ss = 128, Hn = 1024, En = 512, Cn = 512, Vn = 32000;
constexpr size_t PL = 1024u * 1024u;

using short8 = __attribute__((ext_vector_type(8))) short;
using f32x4  = __attribute__((ext_vector_type(4))) float;

// ---- static device scratch (all planes rewritten in-launch before read) ----
__device__ __align__(1024) u16 g_hh[2][PL];   // h ping-pong, hi
__device__ __align__(1024) u16 g_hl[2][PL];   // h ping-pong, lo
__device__ __align__(1024) u16 g_yh[PL], g_yl[PL];
__device__ __align__(1024) u16 g_zh[PL], g_zl[PL];
__device__ __align__(1024) float g_proj[(size_t)Vn * Hn];  // emb@Wih^T + bih + bhh
// bf16 hi/lo split tables (recomputed every launch; deterministic)
__device__ __align__(1024) u16 t_eh[(size_t)Vn * En], t_el[(size_t)Vn * En];
__device__ __align__(1024) u16 t_xh[(size_t)Hn * En], t_xl[(size_t)Hn * En];  // Wih
__device__ __align__(1024) u16 t_hh[(size_t)Hn * Hn], t_hl[(size_t)Hn * Hn];  // Whh
__device__ __align__(1024) u16 t_1h[(size_t)Hn * Hn], t_1l[(size_t)Hn * Hn];  // W1
__device__ __align__(1024) u16 t_2h[(size_t)Cn * Hn], t_2l[(size_t)Cn * Hn];  // W2

__device__ __forceinline__ void gl16(const void* g, void* l) {
  __builtin_amdgcn_global_load_lds((const __attribute__((address_space(1))) void*)g,
                                   (__attribute__((address_space(3))) void*)l, 16, 0, 0);
}
__device__ __forceinline__ unsigned f2bf(float f) {
  unsigned u = __float_as_uint(f);
  return (u + 0x7fffu + ((u >> 16) & 1u)) >> 16;
}
__device__ __forceinline__ float bf2f(unsigned u) { return __uint_as_float(u << 16); }

// fused hi/lo split of all 5 fp32 tables (one launch; same arithmetic as before)
__global__ void cvt_all(const float* __restrict__ emb, const float* __restrict__ Wih,
                        const float* __restrict__ Whh, const float* __restrict__ W1,
                        const float* __restrict__ W2) {
  constexpr size_t N0 = (size_t)Vn * En;            // emb
  constexpr size_t N1 = N0 + (size_t)Hn * En;       // +Wih
  constexpr size_t N2 = N1 + (size_t)Hn * Hn;       // +Whh
  constexpr size_t N3 = N2 + (size_t)Hn * Hn;       // +W1
  constexpr size_t N4 = N3 + (size_t)Cn * Hn;       // +W2
  const size_t stride = (size_t)gridDim.x * blockDim.x;
  for (size_t i = (size_t)blockIdx.x * blockDim.x + threadIdx.x; i < N4; i += stride) {
    const float* src; u16 *hi, *lo; size_t o;
    if (i < N0)      { src = emb; hi = t_eh; lo = t_el; o = i; }
    else if (i < N1) { src = Wih; hi = t_xh; lo = t_xl; o = i - N0; }
    else if (i < N2) { src = Whh; hi = t_hh; lo = t_hl; o = i - N1; }
    else if (i < N3) { src = W1;  hi = t_1h; lo = t_1l; o = i - N2; }
    else             { src = W2;  hi = t_2h; lo = t_2l; o = i - N3; }
    const float v = src[o];
    const unsigned h = f2bf(v);
    hi[o] = (u16)h;
    lo[o] = (u16)f2bf(v - bf2f(h));
  }
}

// Shared GEMM-tile prolog (16x16 shape; mlp_k — unchanged, green).
#define GEMM_PROLOG_NOBID()                                                    \
  const int tid = threadIdx.x;                                                 \
  const int w = tid >> 6, l = tid & 63;                                        \
  const int wr = w & 3, wc = w >> 2;                                           \
  const int lrow = l & 15, lk = l >> 4;                                        \
  const int sr = tid >> 3, p = tid & 7;                                        \
  const int sby = ((p ^ (sr & 7)) << 4);                                       \
  const int arow = (wr << 4) + lrow;                                           \
  int aoff[2], bboff[2][2];                                                    \
  _Pragma("unroll") for (int s = 0; s < 2; ++s)                                \
      aoff[s] = arow * 128 + ((s * 64 + lk * 16) ^ ((arow & 7) << 4));         \
  _Pragma("unroll") for (int n = 0; n < 2; ++n) {                              \
    const int jl = (wc << 5) + (n << 4) + lrow;                                \
    _Pragma("unroll") for (int s = 0; s < 2; ++s)                              \
        bboff[n][s] = jl * 128 + ((s * 64 + lk * 16) ^ ((jl & 7) << 4));       \
  }
#define GEMM_PROLOG() const int bid = blockIdx.x; GEMM_PROLOG_NOBID()

#define GEMM_MFMA(ca, cb)                                                      \
  _Pragma("unroll") for (int s = 0; s < 2; ++s) {                              \
    short8 a = *(const short8*)((ca) + aoff[s]);                               \
    _Pragma("unroll") for (int n = 0; n < 2; ++n) {                            \
      short8 b = *(const short8*)((cb) + bboff[n][s]);                         \
      acc[n] = __builtin_amdgcn_mfma_f32_16x16x32_bf16(a, b, acc[n], 0, 0, 0); \
    }                                                                          \
  }

// proj[v][j] = emb[v] @ Wih^T + bih[j] + bhh[j]
// r22: 64v x 128j tiles (grid 4000) -> each block amortizes the emb read over
// 2x more output cols; total E traffic ~halves. Same 8-chunk ring-2 schedule,
// per-output accumulation order unchanged (g_proj bit-identical to r15).
__global__ void __launch_bounds__(512) proj_k(const float* __restrict__ bih,
                                              const float* __restrict__ bhh) {
  extern __shared__ char ring[];   // 2 slots x {Eh 8K | El 8K | Xh 16K | Xl 16K}
  const int tid = threadIdx.x, bid = blockIdx.x;
  const int w = tid >> 6, l = tid & 63;
  const int wr = w & 3, wc = w >> 2;
  const int lrow = l & 15, lk = l >> 4;
  const int sr = tid >> 3, p = tid & 7;
  const int sby = ((p ^ (sr & 7)) << 4);
  const int sby2 = ((p ^ ((sr + 64) & 7)) << 4);   // rows 64..127 (same &7 -> ==sby)
  const int v0 = (bid % 500) << 6;
  const int j0 = (bid / 500) << 7;   // 128-wide j tile

  const int arow = (wr << 4) + lrow;
  int aoff[2], bboff[4][2];
#pragma unroll
  for (int s = 0; s < 2; ++s)
    aoff[s] = arow * 128 + ((s * 64 + lk * 16) ^ ((arow & 7) << 4));
#pragma unroll
  for (int n = 0; n < 4; ++n) {
    const int jl = (wc << 6) + (n << 4) + lrow;    // 0..127
#pragma unroll
    for (int s = 0; s < 2; ++s)
      bboff[n][s] = jl * 128 + ((s * 64 + lk * 16) ^ ((jl & 7) << 4));
  }

  f32x4 acc[4];
#pragma unroll
  for (int n = 0; n < 4; ++n) {
    const float bs = bih[j0 + (wc << 6) + (n << 4) + lrow] +
                     bhh[j0 + (wc << 6) + (n << 4) + lrow];
#pragma unroll
    for (int ri = 0; ri < 4; ++ri) acc[n][ri] = bs;
  }

  // slot layout: Eh[0,8K) El[8K,16K) Xh[16K,32K) Xl[32K,48K); 6 gl16/thread
  auto stage = [&](int c) {
    char* sl = ring + (c & 1) * 49152;
    const int kb = c * 128;
    gl16((const char*)t_eh + (size_t)(v0 + sr) * 1024 + kb + sby, sl + w * 1024);
    gl16((const char*)t_el + (size_t)(v0 + sr) * 1024 + kb + sby, sl + 8192 + w * 1024);
    gl16((const char*)t_xh + (size_t)(j0 + sr) * 1024 + kb + sby, sl + 16384 + w * 1024);
    gl16((const char*)t_xh + (size_t)(j0 + 64 + sr) * 1024 + kb + sby2,
         sl + 24576 + w * 1024);
    gl16((const char*)t_xl + (size_t)(j0 + sr) * 1024 + kb + sby, sl + 32768 + w * 1024);
    gl16((const char*)t_xl + (size_t)(j0 + 64 + sr) * 1024 + kb + sby2,
         sl + 40960 + w * 1024);
  };
  stage(0); stage(1);
  for (int c = 0; c < 8; ++c) {
    // ledger: outstanding before wait = (c==0: bias8+12 : 12); drain all but
    // next chunk's 6 -> vmcnt(6); last iter 0. (bias loads are oldest, drained
    // by iter-0's wait; their VALU use already waited via compiler s_waitcnt.)
    if (c < 7) asm volatile("s_waitcnt vmcnt(6)" ::: "memory");
    else       asm volatile("s_waitcnt vmcnt(0)" ::: "memory");
    __builtin_amdgcn_s_barrier();
    __builtin_amdgcn_sched_barrier(0);
    const char* sl = ring + (c & 1) * 49152;
#pragma unroll
    for (int s = 0; s < 2; ++s) {
      short8 aH = *(const short8*)(sl + aoff[s]);
      short8 aL = *(const short8*)(sl + 8192 + aoff[s]);
#pragma unroll
      for (int n = 0; n < 4; ++n) {
        short8 bH = *(const short8*)(sl + 16384 + bboff[n][s]);
        short8 bL = *(const short8*)(sl + 32768 + bboff[n][s]);
        acc[n] = __builtin_amdgcn_mfma_f32_16x16x32_bf16(aH, bH, acc[n], 0, 0, 0);
        acc[n] = __builtin_amdgcn_mfma_f32_16x16x32_bf16(aL, bH, acc[n], 0, 0, 0);
        acc[n] = __builtin_amdgcn_mfma_f32_16x16x32_bf16(aH, bL, acc[n], 0, 0, 0);
      }
    }
    __builtin_amdgcn_s_barrier();
    if (c + 2 < 8) stage(c + 2);
  }
#pragma unroll
  for (int n = 0; n < 4; ++n) {
    const int j = j0 + (wc << 6) + (n << 4) + lrow;
#pragma unroll
    for (int ri = 0; ri < 4; ++ri)
      g_proj[(size_t)(v0 + (wr << 4) + lk * 4 + ri) * 1024 + j] = acc[n][ri];
  }
}

// One RNN step — r16 VERBATIM (best known: 11.4 µs/step): 16 k=64 chunks,
// ring-4, prefetch dist 3, counted vmcnt, ONE barrier per chunk.
__global__ void __launch_bounds__(512) step_k(const int* __restrict__ x_in,
                                              const int* __restrict__ x_len, int t) {
  extern __shared__ char ring[];   // 4 slots x {Ah 8K | Al 8K | Wh 8K | Wl 8K}
  __shared__ int toks[64];
  GEMM_PROLOG()
  const int b0 = (bid & 15) << 6, j0 = (bid >> 4) << 6;
  const u16* hinh = g_hh[t & 1];
  const u16* hinl = g_hl[t & 1];
  u16* houth = g_hh[(t + 1) & 1];
  u16* houtl = g_hl[(t + 1) & 1];

  if (tid < 64) toks[tid] = x_in[(b0 + tid) * Ss + t];
  __syncthreads();

  float pj[2][4];
#pragma unroll
  for (int n = 0; n < 2; ++n) {
    const int j = j0 + (wc << 5) + (n << 4) + lrow;
#pragma unroll
    for (int ri = 0; ri < 4; ++ri)
      pj[n][ri] = g_proj[(size_t)toks[(wr << 4) + lk * 4 + ri] * 1024 + j];
  }
  asm volatile("" ::: "memory");

  f32x4 acc[2];
  acc[0] = (f32x4){0.f, 0.f, 0.f, 0.f}; acc[1] = acc[0];

  if (t > 0) {
    auto stage = [&](int c) {
      char* sl = ring + (c & 3) * 32768;
      const int kb = c * 128;
      gl16((const char*)hinh + (size_t)(b0 + sr) * 2048 + kb + sby, sl + w * 1024);
      gl16((const char*)hinl + (size_t)(b0 + sr) * 2048 + kb + sby, sl + 8192 + w * 1024);
      gl16((const char*)t_hh + (size_t)(j0 + sr) * 2048 + kb + sby, sl + 16384 + w * 1024);
      gl16((const char*)t_hl + (size_t)(j0 + sr) * 2048 + kb + sby, sl + 24576 + w * 1024);
    };
    stage(0); stage(1); stage(2);
    for (int c = 0; c < 16; ++c) {
      const int left = 15 - c;
      if (left >= 2)      asm volatile("s_waitcnt vmcnt(8)" ::: "memory");
      else if (left == 1) asm volatile("s_waitcnt vmcnt(4)" ::: "memory");
      else                asm volatile("s_waitcnt vmcnt(0)" ::: "memory");
      __builtin_amdgcn_s_barrier();
      __builtin_amdgcn_sched_barrier(0);
      if (c + 3 < 16) stage(c + 3);
      const char* sl = ring + (c & 3) * 32768;
#pragma unroll
      for (int s = 0; s < 2; ++s) {
        short8 aH = *(const short8*)(sl + aoff[s]);
        short8 aL = *(const short8*)(sl + 8192 + aoff[s]);
#pragma unroll
        for (int n = 0; n < 2; ++n) {
          short8 bH = *(const short8*)(sl + 16384 + bboff[n][s]);
          short8 bL = *(const short8*)(sl + 24576 + bboff[n][s]);
          acc[n] = __builtin_amdgcn_mfma_f32_16x16x32_bf16(aH, bH, acc[n], 0, 0, 0);
          acc[n] = __builtin_amdgcn_mfma_f32_16x16x32_bf16(aL, bH, acc[n], 0, 0, 0);
          acc[n] = __builtin_amdgcn_mfma_f32_16x16x32_bf16(aH, bL, acc[n], 0, 0, 0);
        }
      }
    }
  }

#pragma unroll
  for (int n = 0; n < 2; ++n) {
    const int j = j0 + (wc << 5) + (n << 4) + lrow;
#pragma unroll
    for (int ri = 0; ri < 4; ++ri) {
      const int brow = b0 + (wr << 4) + lk * 4 + ri;
      const float v = tanhf(acc[n][ri] + pj[n][ri]);
      const unsigned hi = f2bf(v);
      const unsigned lo = f2bf(v - bf2f(hi));
      const size_t off = (size_t)brow * 1024 + j;
      houth[off] = (u16)hi;
      houtl[off] = (u16)lo;
      if (x_len[brow] == t + 1) { g_yh[off] = (u16)hi; g_yl[off] = (u16)lo; }
    }
  }
}

// MLP (unchanged from r12, green)
__global__ void __launch_bounds__(512) mlp_k(const float* __restrict__ bias,
                                             float* __restrict__ out, int mode) {
  __shared__ char sA[16384];
  __shared__ char sB[16384];
  GEMM_PROLOG()
  const int b0 = (bid & 15) << 6, j0 = (bid >> 4) << 6;
  const u16* ah = mode ? g_zh : g_yh;
  const u16* al = mode ? g_zl : g_yl;
  const u16* bh = mode ? t_2h : t_1h;
  const u16* bl = mode ? t_2l : t_1l;

  f32x4 acc[2];
#pragma unroll
  for (int n = 0; n < 2; ++n) {
    const float bs = bias[j0 + (wc << 5) + (n << 4) + lrow];
#pragma unroll
    for (int ri = 0; ri < 4; ++ri) acc[n][ri] = bs;
  }

  auto stage = [&](int c) {
    char* da = sA + (c & 1) * 8192;
    char* db = sB + (c & 1) * 8192;
    const u16* ap = (c >= 16 && c < 32) ? al : ah;
    const u16* bp = (c < 32) ? bh : bl;
    const int kb = (c & 15) * 128;
    gl16((const char*)ap + (size_t)(b0 + sr) * 2048 + kb + sby, da + w * 1024);
    gl16((const char*)bp + (size_t)(j0 + sr) * 2048 + kb + sby, db + w * 1024);
  };
  stage(0);
  __syncthreads();
  for (int c = 0; c < 48; ++c) {
    const char* ca = sA + (c & 1) * 8192;
    const char* cb = sB + (c & 1) * 8192;
    if (c < 47) stage(c + 1);
    GEMM_MFMA(ca, cb)
    __syncthreads();
  }

#pragma unroll
  for (int n = 0; n < 2; ++n) {
    const int j = j0 + (wc << 5) + (n << 4) + lrow;
#pragma unroll
    for (int ri = 0; ri < 4; ++ri) {
      const int brow = b0 + (wr << 4) + lk * 4 + ri;
      if (mode == 0) {
        const float v = fmaxf(acc[n][ri], 0.f);
        const unsigned hi = f2bf(v);
        const unsigned lo = f2bf(v - bf2f(hi));
        const size_t off = (size_t)brow * 1024 + j;
        g_zh[off] = (u16)hi;
        g_zl[off] = (u16)lo;
      } else {
        out[(size_t)brow * 512 + j] = acc[n][ri];
      }
    }
  }
}

extern "C" void kernel_launch(void* const* d_in, const int* in_sizes, int n_in,
                              void* d_out, int out_size, void* d_ws, size_t ws_size,
                              hipStream_t stream) {
  const int*   x_in  = (const int*)d_in[0];
  const int*   x_len = (const int*)d_in[1];
  const float* emb = (const float*)d_in[2];
  const float* Wih = (const float*)d_in[3];
  const float* Whh = (const float*)d_in[4];
  const float* bih = (const float*)d_in[5];
  const float* bhh = (const float*)d_in[6];
  const float* W1  = (const float*)d_in[7];
  const float* b1  = (const float*)d_in[8];
  const float* W2  = (const float*)d_in[9];
  const float* b2  = (const float*)d_in[10];
  float* out = (float*)d_out;

  (void)hipFuncSetAttribute((const void*)step_k,
                            hipFuncAttributeMaxDynamicSharedMemorySize, 131072);
  (void)hipFuncSetAttribute((const void*)proj_k,
                            hipFuncAttributeMaxDynamicSharedMemorySize, 98304);

  cvt_all<<<dim3(4096), dim3(256), 0, stream>>>(emb, Wih, Whh, W1, W2);

  proj_k<<<dim3(4000), dim3(512), 98304, stream>>>(bih, bhh);

  for (int t = 0; t < Ss; ++t)
    step_k<<<dim3(256), dim3(512), 131072, stream>>>(x_in, x_len, t);

  mlp_k<<<dim3(256), dim3(512), 0, stream>>>(b1, nullptr, 0);
  mlp_k<<<dim3(128), dim3(512), 0, stream>>>(b2, out, 1);
}